// Round 6
// baseline (257.007 us; speedup 1.0000x reference)
//
#include <hip/hip_runtime.h>
#include <math.h>

#define B_  8
#define E_  1024
#define D_  256
#define H_  16
#define FF_ 1024
#define M_  (B_ * E_)   // 8192 rows

typedef __attribute__((ext_vector_type(8))) short short8;
typedef __attribute__((ext_vector_type(4))) float f32x4;
typedef unsigned short bf16u;

#define GLOAD_LDS16(g, l) __builtin_amdgcn_global_load_lds( \
    (const __attribute__((address_space(1))) void*)(g), \
    (__attribute__((address_space(3))) void*)(l), 16, 0, 0)

// raw barrier pair for pipelined K-loops (bypasses __syncthreads' vmcnt(0)
// drain). LGKM_BAR: prev buffer's LDS reads retired before overwrite.
// VM_BAR(N): all but the N newest vector-mem ops retired (N = dma count of
// the next tile) -> current tile complete, next tile still in flight.
#define LGKM_BAR()  asm volatile("s_waitcnt lgkmcnt(0)\ns_barrier" ::: "memory")
#define VM_BAR(N)   asm volatile("s_waitcnt vmcnt(" #N ")\ns_barrier" ::: "memory")

__device__ __forceinline__ unsigned short f2bf(float f) {
  union { float f; unsigned u; } c; c.f = f;
  unsigned r = c.u + 0x7fffu + ((c.u >> 16) & 1u);   // RNE
  return (unsigned short)(r >> 16);
}
__device__ __forceinline__ float gelu_exact(float x) {
  return 0.5f * x * (1.0f + erff(x * 0.70710678118654752f));
}

// ---------------------------------------------------------------------------
// Pipelined bf16 MFMA GEMM (unchanged from r5 — passing). Only used for QKV.
// ---------------------------------------------------------------------------
template<int K_, int EPI>
__global__ __launch_bounds__(256) void mm_p(
    const bf16u* __restrict__ A, const bf16u* __restrict__ Wt,
    const float* __restrict__ bias, void* __restrict__ Cout, int N)
{
  constexpr int BM = 128, BN = 64, KT = K_ / 64;
  constexpr int MT = 4, NT = 2;
  __shared__ bf16u As[2][BM * 64];
  __shared__ bf16u Bs[2][BN * 64];

  const int t = threadIdx.x;
  const int l15 = t & 15, quad = (t >> 4) & 3;
  const int w = t >> 6, wm = w >> 1, wn = w & 1;
  const int m0 = blockIdx.x * BM, n0 = blockIdx.y * BN;

  auto stage = [&](int kt, int pb) {
    const int k0 = kt * 64;
#pragma unroll
    for (int p = 0; p < 4; ++p) {
      int g = p * 256 + t;
      int m = g & 127, c = g >> 7;
      GLOAD_LDS16(A + (size_t)(m0 + m) * K_ + k0 + c * 8, &As[pb][g * 8]);
    }
#pragma unroll
    for (int p = 0; p < 2; ++p) {
      int g = p * 256 + t;
      int n = g & 63, c = g >> 6;
      GLOAD_LDS16(Wt + (size_t)(n0 + n) * K_ + k0 + c * 8, &Bs[pb][g * 8]);
    }
  };

  f32x4 acc[MT][NT];
  const f32x4 z4 = {0.f, 0.f, 0.f, 0.f};
#pragma unroll
  for (int i = 0; i < MT; ++i)
#pragma unroll
    for (int j = 0; j < NT; ++j) acc[i][j] = z4;

  stage(0, 0);
#pragma unroll
  for (int kt = 0; kt < KT; ++kt) {
    LGKM_BAR();
    if (kt + 1 < KT) { stage(kt + 1, (kt + 1) & 1); VM_BAR(6); }
    else             { VM_BAR(0); }
    const bf16u* Ab = As[kt & 1];
    const bf16u* Bb = Bs[kt & 1];
#pragma unroll
    for (int s = 0; s < 2; ++s) {
      const int cc = s * 4 + quad;
      short8 af[MT], bfr[NT];
#pragma unroll
      for (int mt = 0; mt < MT; ++mt)
        af[mt] = *(const short8*)(Ab + (cc * BM + wm * 64 + mt * 16 + l15) * 8);
#pragma unroll
      for (int nt = 0; nt < NT; ++nt)
        bfr[nt] = *(const short8*)(Bb + (cc * BN + wn * 32 + nt * 16 + l15) * 8);
#pragma unroll
      for (int mt = 0; mt < MT; ++mt)
#pragma unroll
        for (int nt = 0; nt < NT; ++nt)
          acc[mt][nt] = __builtin_amdgcn_mfma_f32_16x16x32_bf16(
              af[mt], bfr[nt], acc[mt][nt], 0, 0, 0);
    }
  }

#pragma unroll
  for (int mt = 0; mt < MT; ++mt) {
#pragma unroll
    for (int nt = 0; nt < NT; ++nt) {
      int col = n0 + wn * 32 + nt * 16 + l15;
      float bia = bias[col];
#pragma unroll
      for (int r = 0; r < 4; ++r) {
        int row = m0 + wm * 64 + mt * 16 + quad * 4 + r;
        size_t idx = (size_t)row * N + col;
        float v = acc[mt][nt][r] + bia;
        if (EPI == 2) ((bf16u*)Cout)[idx] = f2bf(gelu_exact(v));
        else          ((bf16u*)Cout)[idx] = f2bf(v);
      }
    }
  }
}

// ---------------------------------------------------------------------------
// Pipelined fused GEMM + bias + residual + LayerNorm (unchanged from r5).
// Used for Wo+LN1. BM=32, BN=256 full row, 4 waves 1x4.
// ---------------------------------------------------------------------------
template<int K_, int LN1>
__global__ __launch_bounds__(256) void mm_ln_p(
    const bf16u* __restrict__ A, const bf16u* __restrict__ Wt,
    const float* __restrict__ bias, const float* __restrict__ R,
    const float* __restrict__ gam, const float* __restrict__ bet,
    float* __restrict__ Yf, bf16u* __restrict__ Yb)
{
  constexpr int KT = K_ / 64;
  __shared__ bf16u As[2][32 * 64];
  __shared__ bf16u Bs[2][256 * 64];
  __shared__ float red[2][32][4];

  const int t = threadIdx.x;
  const int l15 = t & 15, quad = (t >> 4) & 3;
  const int w = t >> 6;
  const int m0 = blockIdx.x * 32;

  auto stage = [&](int kt, int pb) {
    const int k0 = kt * 64;
    GLOAD_LDS16(A + (size_t)(m0 + (t & 31)) * K_ + k0 + (t >> 5) * 8,
                &As[pb][t * 8]);
#pragma unroll
    for (int p = 0; p < 8; ++p) {
      int g = p * 256 + t;
      GLOAD_LDS16(Wt + (size_t)(g & 255) * K_ + k0 + (g >> 8) * 8,
                  &Bs[pb][g * 8]);
    }
  };

  f32x4 acc[2][4];
  const f32x4 z4 = {0.f, 0.f, 0.f, 0.f};
#pragma unroll
  for (int i = 0; i < 2; ++i)
#pragma unroll
    for (int j = 0; j < 4; ++j) acc[i][j] = z4;

  stage(0, 0);
#pragma unroll
  for (int kt = 0; kt < KT; ++kt) {
    LGKM_BAR();
    if (kt + 1 < KT) { stage(kt + 1, (kt + 1) & 1); VM_BAR(9); }
    else             { VM_BAR(0); }
    const bf16u* Ab = As[kt & 1];
    const bf16u* Bb = Bs[kt & 1];
#pragma unroll
    for (int s = 0; s < 2; ++s) {
      const int cc = s * 4 + quad;
      short8 af[2], bfr[4];
#pragma unroll
      for (int mt = 0; mt < 2; ++mt)
        af[mt] = *(const short8*)(Ab + (cc * 32 + mt * 16 + l15) * 8);
#pragma unroll
      for (int nt = 0; nt < 4; ++nt)
        bfr[nt] = *(const short8*)(Bb + (cc * 256 + w * 64 + nt * 16 + l15) * 8);
#pragma unroll
      for (int mt = 0; mt < 2; ++mt)
#pragma unroll
        for (int nt = 0; nt < 4; ++nt)
          acc[mt][nt] = __builtin_amdgcn_mfma_f32_16x16x32_bf16(
              af[mt], bfr[nt], acc[mt][nt], 0, 0, 0);
    }
  }

  float ga[4], be4[4], bi[4];
#pragma unroll
  for (int nt = 0; nt < 4; ++nt) {
    int col = w * 64 + nt * 16 + l15;
    bi[nt] = bias[col]; ga[nt] = gam[col]; be4[nt] = bet[col];
  }
#pragma unroll
  for (int mt = 0; mt < 2; ++mt)
#pragma unroll
    for (int nt = 0; nt < 4; ++nt) {
      int col = w * 64 + nt * 16 + l15;
#pragma unroll
      for (int r = 0; r < 4; ++r) {
        int row = m0 + mt * 16 + quad * 4 + r;
        acc[mt][nt][r] += bi[nt] + R[(size_t)row * 256 + col];
      }
    }

  float s1[2][4], s2[2][4];
#pragma unroll
  for (int mt = 0; mt < 2; ++mt)
#pragma unroll
    for (int r = 0; r < 4; ++r) {
      float a = 0.f, b = 0.f;
#pragma unroll
      for (int nt = 0; nt < 4; ++nt) {
        float v = acc[mt][nt][r];
        a += v; b += v * v;
      }
      s1[mt][r] = a; s2[mt][r] = b;
    }
#pragma unroll
  for (int off = 1; off <= 8; off <<= 1)
#pragma unroll
    for (int mt = 0; mt < 2; ++mt)
#pragma unroll
      for (int r = 0; r < 4; ++r) {
        s1[mt][r] += __shfl_xor(s1[mt][r], off, 64);
        s2[mt][r] += __shfl_xor(s2[mt][r], off, 64);
      }
  if (l15 == 0) {
#pragma unroll
    for (int mt = 0; mt < 2; ++mt)
#pragma unroll
      for (int r = 0; r < 4; ++r) {
        int row32 = mt * 16 + quad * 4 + r;
        red[0][row32][w] = s1[mt][r];
        red[1][row32][w] = s2[mt][r];
      }
  }
  LGKM_BAR();

#pragma unroll
  for (int mt = 0; mt < 2; ++mt)
#pragma unroll
    for (int r = 0; r < 4; ++r) {
      int row32 = mt * 16 + quad * 4 + r;
      float4 sa = *(const float4*)&red[0][row32][0];
      float4 sb = *(const float4*)&red[1][row32][0];
      float sum = sa.x + sa.y + sa.z + sa.w;
      float sq  = sb.x + sb.y + sb.z + sb.w;
      float mu  = sum * (1.f / 256.f);
      float var = sq * (1.f / 256.f) - mu * mu;
      float rs  = 1.f / sqrtf(var + 1e-5f);
      int row = m0 + row32;
#pragma unroll
      for (int nt = 0; nt < 4; ++nt) {
        int col = w * 64 + nt * 16 + l15;
        float y = (acc[mt][nt][r] - mu) * rs * ga[nt] + be4[nt];
        size_t idx = (size_t)row * 256 + col;
        Yf[idx] = y;
        if (LN1) Yb[idx] = f2bf(y);
      }
    }
}

// ---------------------------------------------------------------------------
// Fully-fused FFN: out = LN2( x1 + (gelu(x1b@Wf1+bf1))@Wf2 + bf2 ).
// One block per 32 rows (grid 256, 1 block/CU). The 32x1024 hidden tile
// lives entirely in LDS (ffh, +8/row pad -> row stride 2064 B, 2-way banks).
// Phase 1: A-frags prefetched to registers (no in-loop VMEM except the
// staging DMAs -> VM_BAR counts stay exact); Wf1t streamed in 16 dbuf'd
// 32 KB n-chunks; gelu'd bf16 written to ffh.
// Phase 2: K=1024 GEMM, A-frags ds_read from ffh, Wf2t streamed through the
// same dbuf; epilogue = bias + residual(x1) + LN2 (mm_ln pattern).
// Biases/gamma/beta parked in LDS so pipelined loops issue no stray VMEM.
// Static LDS ~138 KB (gfx950 LDS pool is 160 KB; r1 ran 70656 B fine).
// ---------------------------------------------------------------------------
__global__ __launch_bounds__(256) void ffn_k(
    const bf16u* __restrict__ x1b, const float* __restrict__ x1,
    const bf16u* __restrict__ Wf1t, const float* __restrict__ bf1,
    const bf16u* __restrict__ Wf2t, const float* __restrict__ bf2,
    const float* __restrict__ g2, const float* __restrict__ b2,
    float* __restrict__ out)
{
  __shared__ bf16u Bst[2][2048 * 8];   // 2 x 32 KB weight staging
  __shared__ bf16u ffh[32][1032];      // 66 KB hidden tile (pad 8)
  __shared__ float red[2][32][4];
  __shared__ float bfl[1024];          // bf1
  __shared__ float cst[3 * 256];       // bf2 | g2 | b2

  const int t = threadIdx.x;
  const int l15 = t & 15, quad = (t >> 4) & 3;
  const int w = t >> 6;
  const int wm = w >> 1, wn = w & 1;   // phase-1 wave tiling (2x2 over 32x64)
  const int m0 = blockIdx.x * 32;

  // park small constants in LDS (plain loads; retire before first VM_BAR)
  for (int i = t; i < 1024; i += 256) bfl[i] = bf1[i];
  if (t < 256) { cst[t] = bf2[t]; cst[256 + t] = g2[t]; cst[512 + t] = b2[t]; }

  // phase-1 A fragments: x1b[m0+wm*16+l15][k], k = s*32 + quad*8 (8 frags)
  short8 afx[8];
  {
    const bf16u* ap = x1b + (size_t)(m0 + wm * 16 + l15) * 256 + quad * 8;
#pragma unroll
    for (int s = 0; s < 8; ++s)
      afx[s] = *(const short8*)(ap + s * 32);
  }

  auto stage1 = [&](int j, int pb) {   // Wf1t rows j*64..+64, all K=256
#pragma unroll
    for (int p = 0; p < 8; ++p) {
      int g = p * 256 + t;             // g = c*64 + n  (c=0..31, n=0..63)
      GLOAD_LDS16(Wf1t + (size_t)(j * 64 + (g & 63)) * 256 + (g >> 6) * 8,
                  &Bst[pb][g * 8]);
    }
  };
  auto stage2 = [&](int kt, int pb) {  // Wf2t all 256 rows, k-chunk kt*64
#pragma unroll
    for (int p = 0; p < 8; ++p) {
      int g = p * 256 + t;             // g = c*256 + n (c=0..7, n=0..255)
      GLOAD_LDS16(Wf2t + (size_t)(g & 255) * 1024 + kt * 64 + (g >> 8) * 8,
                  &Bst[pb][g * 8]);
    }
  };

  const f32x4 z4 = {0.f, 0.f, 0.f, 0.f};

  // ---------------- phase 1: hidden = gelu(x1b @ Wf1 + bf1) ----------------
  stage1(0, 0);
#pragma unroll
  for (int j = 0; j < 16; ++j) {
    LGKM_BAR();
    if (j + 1 < 16) { stage1(j + 1, (j + 1) & 1); VM_BAR(8); }
    else            { VM_BAR(0); }
    const bf16u* Bb = Bst[j & 1];
    f32x4 acc1[2] = {z4, z4};
#pragma unroll
    for (int s = 0; s < 8; ++s) {
      const int cc = s * 4 + quad;
      short8 bfr[2];
#pragma unroll
      for (int nt = 0; nt < 2; ++nt)
        bfr[nt] = *(const short8*)(Bb + (cc * 64 + wn * 32 + nt * 16 + l15) * 8);
#pragma unroll
      for (int nt = 0; nt < 2; ++nt)
        acc1[nt] = __builtin_amdgcn_mfma_f32_16x16x32_bf16(
            afx[s], bfr[nt], acc1[nt], 0, 0, 0);
    }
    // gelu epilogue -> ffh (C-layout: col=l15, row=quad*4+r)
#pragma unroll
    for (int nt = 0; nt < 2; ++nt) {
      int lcol = wn * 32 + nt * 16 + l15;
      float bia = bfl[j * 64 + lcol];
#pragma unroll
      for (int r = 0; r < 4; ++r)
        ffh[wm * 16 + quad * 4 + r][j * 64 + lcol] =
            f2bf(gelu_exact(acc1[nt][r] + bia));
    }
  }

  // ---------------- phase 2: out_row = hidden @ Wf2, then LN2 --------------
  f32x4 acc[2][4];
#pragma unroll
  for (int i = 0; i < 2; ++i)
#pragma unroll
    for (int j = 0; j < 4; ++j) acc[i][j] = z4;

  stage2(0, 0);
#pragma unroll
  for (int kt = 0; kt < 16; ++kt) {
    LGKM_BAR();   // also publishes the last ffh writes before first reads
    if (kt + 1 < 16) { stage2(kt + 1, (kt + 1) & 1); VM_BAR(8); }
    else             { VM_BAR(0); }
    const bf16u* Bb = Bst[kt & 1];
#pragma unroll
    for (int s = 0; s < 2; ++s) {
      const int cc = s * 4 + quad;
      short8 af[2], bfr[4];
#pragma unroll
      for (int mt = 0; mt < 2; ++mt)
        af[mt] = *(const short8*)&ffh[mt * 16 + l15][kt * 64 + s * 32 + quad * 8];
#pragma unroll
      for (int nt = 0; nt < 4; ++nt)
        bfr[nt] = *(const short8*)(Bb + (cc * 256 + w * 64 + nt * 16 + l15) * 8);
#pragma unroll
      for (int mt = 0; mt < 2; ++mt)
#pragma unroll
        for (int nt = 0; nt < 4; ++nt)
          acc[mt][nt] = __builtin_amdgcn_mfma_f32_16x16x32_bf16(
              af[mt], bfr[nt], acc[mt][nt], 0, 0, 0);
    }
  }

  // ---- epilogue: bias + residual(x1) + LN2 -> out fp32 ----
  float ga[4], be4[4], bi[4];
#pragma unroll
  for (int nt = 0; nt < 4; ++nt) {
    int col = w * 64 + nt * 16 + l15;
    bi[nt] = cst[col]; ga[nt] = cst[256 + col]; be4[nt] = cst[512 + col];
  }
#pragma unroll
  for (int mt = 0; mt < 2; ++mt)
#pragma unroll
    for (int nt = 0; nt < 4; ++nt) {
      int col = w * 64 + nt * 16 + l15;
#pragma unroll
      for (int r = 0; r < 4; ++r) {
        int row = m0 + mt * 16 + quad * 4 + r;
        acc[mt][nt][r] += bi[nt] + x1[(size_t)row * 256 + col];
      }
    }

  float s1[2][4], s2[2][4];
#pragma unroll
  for (int mt = 0; mt < 2; ++mt)
#pragma unroll
    for (int r = 0; r < 4; ++r) {
      float a = 0.f, b = 0.f;
#pragma unroll
      for (int nt = 0; nt < 4; ++nt) {
        float v = acc[mt][nt][r];
        a += v; b += v * v;
      }
      s1[mt][r] = a; s2[mt][r] = b;
    }
#pragma unroll
  for (int off = 1; off <= 8; off <<= 1)
#pragma unroll
    for (int mt = 0; mt < 2; ++mt)
#pragma unroll
      for (int r = 0; r < 4; ++r) {
        s1[mt][r] += __shfl_xor(s1[mt][r], off, 64);
        s2[mt][r] += __shfl_xor(s2[mt][r], off, 64);
      }
  if (l15 == 0) {
#pragma unroll
    for (int mt = 0; mt < 2; ++mt)
#pragma unroll
      for (int r = 0; r < 4; ++r) {
        int row32 = mt * 16 + quad * 4 + r;
        red[0][row32][w] = s1[mt][r];
        red[1][row32][w] = s2[mt][r];
      }
  }
  LGKM_BAR();

#pragma unroll
  for (int mt = 0; mt < 2; ++mt)
#pragma unroll
    for (int r = 0; r < 4; ++r) {
      int row32 = mt * 16 + quad * 4 + r;
      float4 sa = *(const float4*)&red[0][row32][0];
      float4 sb = *(const float4*)&red[1][row32][0];
      float sum = sa.x + sa.y + sa.z + sa.w;
      float sq  = sb.x + sb.y + sb.z + sb.w;
      float mu  = sum * (1.f / 256.f);
      float var = sq * (1.f / 256.f) - mu * mu;
      float rs  = 1.f / sqrtf(var + 1e-5f);
      int row = m0 + row32;
#pragma unroll
      for (int nt = 0; nt < 4; ++nt) {
        int col = w * 64 + nt * 16 + l15;
        float y = (acc[mt][nt][r] - mu) * rs * ga[nt] + be4[nt];
        out[(size_t)row * 256 + col] = y;
      }
    }
}

// ---------------------------------------------------------------------------
// One-shot prep (unchanged — passing).
// ---------------------------------------------------------------------------
__global__ __launch_bounds__(256) void prep_k(
    const float* __restrict__ x, bf16u* __restrict__ xb,
    const float* __restrict__ Wq, const float* __restrict__ Wk,
    const float* __restrict__ Wv, const float* __restrict__ Wo,
    bf16u* __restrict__ Wqkvt, bf16u* __restrict__ Wot,
    const float* __restrict__ Wf1, bf16u* __restrict__ Wf1t,
    const float* __restrict__ Wf2, bf16u* __restrict__ Wf2t,
    const float* __restrict__ bq, const float* __restrict__ bk,
    const float* __restrict__ bv, float* __restrict__ bqkv)
{
  __shared__ float tile[32][33];
  const int bid = blockIdx.x;
  const int t = threadIdx.x;

  if (bid < 1024) {
    int i = bid * 256 + t;
    float4 a = ((const float4*)x)[i * 2];
    float4 b = ((const float4*)x)[i * 2 + 1];
    uint4 o;
    o.x = f2bf(a.x) | ((unsigned)f2bf(a.y) << 16);
    o.y = f2bf(a.z) | ((unsigned)f2bf(a.w) << 16);
    o.z = f2bf(b.x) | ((unsigned)f2bf(b.y) << 16);
    o.w = f2bf(b.z) | ((unsigned)f2bf(b.w) << 16);
    ((uint4*)xb)[i] = o;
  } else if (bid < 1792) {
    const float* src; bf16u* dst; int K, N, kb, nb;
    int rr = bid - 1024;
    if (rr < 256) {
      int z = rr >> 6, i = rr & 63;
      src = (z == 0) ? Wq : (z == 1) ? Wk : (z == 2) ? Wv : Wo;
      dst = (z == 0) ? Wqkvt : (z == 1) ? Wqkvt + 65536
          : (z == 2) ? Wqkvt + 131072 : Wot;
      K = 256; N = 256; kb = (i & 7) * 32; nb = (i >> 3) * 32;
    } else if (rr < 512) {
      int i = rr - 256;
      src = Wf1; dst = Wf1t; K = 256; N = 1024;
      kb = (i & 7) * 32; nb = (i >> 3) * 32;
    } else {
      int i = rr - 512;
      src = Wf2; dst = Wf2t; K = 1024; N = 256;
      kb = (i & 31) * 32; nb = (i >> 5) * 32;
    }
    const int tx = t & 31, ty = t >> 5;
#pragma unroll
    for (int r = 0; r < 4; ++r)
      tile[ty + 8 * r][tx] = src[(size_t)(kb + ty + 8 * r) * N + nb + tx];
    __syncthreads();
#pragma unroll
    for (int r = 0; r < 4; ++r)
      dst[(size_t)(nb + ty + 8 * r) * K + kb + tx] = f2bf(tile[tx][ty + 8 * r]);
  } else {
    for (int i = t; i < 768; i += 256)
      bqkv[i] = (i < 256) ? bq[i] : (i < 512) ? bk[i - 256] : bv[i - 512];
  }
}

// ---------------------------------------------------------------------------
// MFMA flash attention (unchanged from round 3 — passing, ~62 us).
// ---------------------------------------------------------------------------
__global__ __launch_bounds__(256) void attn_k(
    const bf16u* __restrict__ qkv, const int* __restrict__ sb,
    const unsigned char* __restrict__ mask, const float* __restrict__ be,
    bf16u* __restrict__ O)
{
  __shared__ bf16u Kl[2][64][40];
  __shared__ bf16u Vt[2][16][72];
  __shared__ bf16u Pl[4][16][40];
  __shared__ float embl[2][6];

  const int t    = threadIdx.x;
  const int b    = blockIdx.z;
  const int hg   = blockIdx.y;
  const int w    = t >> 6;
  const int lane = t & 63;
  const int l15  = lane & 15;
  const int quad = lane >> 4;
  const int q0w  = blockIdx.x * 64 + w * 16;

  if (t < 12) embl[t / 6][t % 6] = be[(t % 6) * 16 + hg * 2 + t / 6];

  {
    float4 z = {0.f, 0.f, 0.f, 0.f};
    float4* kp = (float4*)&Kl[0][0][0];
    for (int i = t; i < 640; i += 256) kp[i] = z;
  }

  short8 qf[2];
#pragma unroll
  for (int hp = 0; hp < 2; ++hp) {
    uint4 v = {0u, 0u, 0u, 0u};
    if (quad < 2)
      v = *(const uint4*)(qkv + ((size_t)(b * E_) + q0w + l15) * 768 +
                          (hg * 2 + hp) * 16 + quad * 8);
    else if (quad == 2)
      v.x = 0x3F80u;
    union { uint4 u; short8 s; } c; c.u = v;
    qf[hp] = c.s;
  }

  const int s_hp   = t >> 7;
  const int s_key  = (t >> 1) & 63;
  const int s_half = t & 1;
  const size_t kvbase = (size_t)b * E_ * 768;
  const int* sbp = sb + ((size_t)b * E_ + q0w) * E_;

  f32x4 accO[2];
  const f32x4 z4 = {0.f, 0.f, 0.f, 0.f};
  accO[0] = z4; accO[1] = z4;
  float lsum[2][4] = {};

  for (int k0 = 0; k0 < E_; k0 += 64) {
    int sbv[2][2][4];
#pragma unroll
    for (int s2 = 0; s2 < 2; ++s2)
#pragma unroll
      for (int f = 0; f < 2; ++f)
#pragma unroll
        for (int r = 0; r < 4; ++r)
          sbv[s2][f][r] = sbp[(size_t)(quad * 4 + r) * E_ + k0 + s2 * 32 + f * 16 + l15];

    __syncthreads();
    {
      const bf16u* kq = qkv + kvbase + (size_t)(k0 + s_key) * 768 + 256 +
                        (hg * 2 + s_hp) * 16 + s_half * 8;
      uint4 kw = *(const uint4*)kq;
      uint4 vw = *(const uint4*)(kq + 256);
      *(uint4*)&Kl[s_hp][s_key][s_half * 8] = kw;
      const int col = (s_key >> 5) * 32 + ((s_key & 15) << 1) + ((s_key >> 4) & 1);
      union { uint4 u; bf16u e[8]; } vc; vc.u = vw;
#pragma unroll
      for (int j = 0; j < 8; ++j)
        Vt[s_hp][s_half * 8 + j][col] = vc.e[j];
      if (s_half == 0) {
        unsigned char mv = mask[b * E_ + k0 + s_key];
        Kl[s_hp][s_key][16] = mv ? (bf16u)0xCF6E : (bf16u)0;
      }
    }
    __syncthreads();

#pragma unroll
    for (int hp = 0; hp < 2; ++hp) {
#pragma unroll
      for (int s2 = 0; s2 < 2; ++s2) {
        short8 kf0 = *(const short8*)&Kl[hp][s2 * 32 + l15][quad * 8];
        short8 kf1 = *(const short8*)&Kl[hp][s2 * 32 + 16 + l15][quad * 8];
        f32x4 sc0 = __builtin_amdgcn_mfma_f32_16x16x32_bf16(qf[hp], kf0, z4, 0, 0, 0);
        f32x4 sc1 = __builtin_amdgcn_mfma_f32_16x16x32_bf16(qf[hp], kf1, z4, 0, 0, 0);
#pragma unroll
        for (int r = 0; r < 4; ++r) {
          float w0 = embl[hp][sbv[s2][0][r]];
          float w1 = embl[hp][sbv[s2][1][r]];
          float p0 = __expf(fmaf(sc0[r], 0.25f, w0));
          float p1 = __expf(fmaf(sc1[r], 0.25f, w1));
          unsigned u0 = __float_as_uint(p0) & 0xffff0000u;
          unsigned u1 = __float_as_uint(p1) & 0xffff0000u;
          lsum[hp][r] += __uint_as_float(u0) + __uint_as_float(u1);
          *(unsigned*)&Pl[w][quad * 4 + r][l15 * 2] = (__float_as_uint(p0) >> 16) | u1;
        }
        short8 pf = *(const short8*)&Pl[w][l15][quad * 8];
        short8 vf = *(const short8*)&Vt[hp][l15][s2 * 32 + quad * 8];
        accO[hp] = __builtin_amdgcn_mfma_f32_16x16x32_bf16(pf, vf, accO[hp], 0, 0, 0);
      }
    }
  }

#pragma unroll
  for (int off = 1; off <= 8; off <<= 1)
#pragma unroll
    for (int hp = 0; hp < 2; ++hp)
#pragma unroll
      for (int r = 0; r < 4; ++r)
        lsum[hp][r] += __shfl_xor(lsum[hp][r], off, 64);

#pragma unroll
  for (int hp = 0; hp < 2; ++hp) {
#pragma unroll
    for (int r = 0; r < 4; ++r) {
      float o = accO[hp][r] / lsum[hp][r];
      O[((size_t)(b * E_) + q0w + quad * 4 + r) * 256 + (hg * 2 + hp) * 16 + l15] = f2bf(o);
    }
  }
}

// ---------------------------------------------------------------------------
extern "C" void kernel_launch(void* const* d_in, const int* in_sizes, int n_in,
                              void* d_out, int out_size, void* d_ws, size_t ws_size,
                              hipStream_t stream) {
  const float* x   = (const float*)d_in[0];
  const int*   sb  = (const int*)d_in[1];
  const unsigned char* mask = (const unsigned char*)d_in[2];
  const float* Wq  = (const float*)d_in[3];
  const float* bq  = (const float*)d_in[4];
  const float* Wk  = (const float*)d_in[5];
  const float* bk  = (const float*)d_in[6];
  const float* Wv  = (const float*)d_in[7];
  const float* bv  = (const float*)d_in[8];
  const float* Wo  = (const float*)d_in[9];
  const float* bo  = (const float*)d_in[10];
  const float* be  = (const float*)d_in[11];
  const float* g1  = (const float*)d_in[12];
  const float* b1  = (const float*)d_in[13];
  const float* Wf1 = (const float*)d_in[14];
  const float* bf1 = (const float*)d_in[15];
  const float* Wf2 = (const float*)d_in[16];
  const float* bf2 = (const float*)d_in[17];
  const float* g2  = (const float*)d_in[18];
  const float* b2  = (const float*)d_in[19];
  float* out = (float*)d_out;

  // workspace layout (byte offsets); peak ~36 MB
  char* ws = (char*)d_ws;
  bf16u* Wqkvt = (bf16u*)(ws + 0);          // 768*256*2
  bf16u* Wot   = (bf16u*)(ws + 393216);     // 256*256*2
  bf16u* Wf1t  = (bf16u*)(ws + 524288);     // 1024*256*2
  bf16u* Wf2t  = (bf16u*)(ws + 1048576);    // 256*1024*2
  float* bqkv  = (float*)(ws + 1572864);    // 768*4
  bf16u* xb    = (bf16u*)(ws + 2097152);    // 4 MB   [dead after qkv gemm]
  bf16u* qkv   = (bf16u*)(ws + 6291456);    // 12 MB  [dead after attn]
  bf16u* att   = (bf16u*)(ws + 18874368);   // 4 MB   [dead after wo gemm]
  float* x1    = (float*)(ws + 23068672);   // 8 MB
  bf16u* x1b   = (bf16u*)(ws + 31457280);   // 4 MB

  dim3 blk(256);

  prep_k<<<1793, blk, 0, stream>>>(x, xb, Wq, Wk, Wv, Wo, Wqkvt, Wot,
                                   Wf1, Wf1t, Wf2, Wf2t, bq, bk, bv, bqkv);

  // QKV projection (N=768) -> qkv bf16
  mm_p<256, 0><<<dim3(64, 12), blk, 0, stream>>>(xb, Wqkvt, bqkv, qkv, 768);

  // MFMA flash attention -> att bf16
  attn_k<<<dim3(16, 8, 8), blk, 0, stream>>>(qkv, sb, mask, be, att);

  // Wo GEMM + bias + residual(x) + LN1 -> x1 fp32, x1b bf16
  mm_ln_p<256, 1><<<256, blk, 0, stream>>>(att, Wot, bo, x, g1, b1, x1, x1b);

  // fused FFN: FF1 + gelu + FF2 + residual(x1) + LN2 -> out fp32
  ffn_k<<<256, blk, 0, stream>>>(x1b, x1, Wf1t, bf1, Wf2t, bf2, g2, b2, out);
}

// Round 8
// 242.675 us; speedup vs baseline: 1.0591x; 1.0591x over previous
//
#include <hip/hip_runtime.h>
#include <math.h>

#define B_  8
#define E_  1024
#define D_  256
#define H_  16
#define FF_ 1024
#define M_  (B_ * E_)   // 8192 rows

typedef __attribute__((ext_vector_type(8))) short short8;
typedef __attribute__((ext_vector_type(4))) float f32x4;
typedef unsigned short bf16u;

#define GLOAD_LDS16(g, l) __builtin_amdgcn_global_load_lds( \
    (const __attribute__((address_space(1))) void*)(g), \
    (__attribute__((address_space(3))) void*)(l), 16, 0, 0)

__device__ __forceinline__ unsigned short f2bf(float f) {
  union { float f; unsigned u; } c; c.f = f;
  unsigned r = c.u + 0x7fffu + ((c.u >> 16) & 1u);   // RNE
  return (unsigned short)(r >> 16);
}
__device__ __forceinline__ float gelu_exact(float x) {
  return 0.5f * x * (1.0f + erff(x * 0.70710678118654752f));
}

// ---------------------------------------------------------------------------
// K-resident bf16 MFMA GEMM. C[M,N] = A[M,K] @ Wt[N,K]^T + bias (+epilogue)
// BM=128, BN=64, BK=128 single-buffered (48 KB LDS -> 3 blocks/CU).
// K=256 GEMMs: 2 stage+compute rounds total (4 barriers); K=1024: 8 rounds.
// 4 waves (2x2), wave tile 64x32 (MT=4, NT=2) — mm_p's proven tiling.
// LDS chunk-major [c][row]: global_load_lds dest lane-linear, frag
// ds_read_b128 256B-contiguous per quad (<=2-way banks, free).
// EPI: 0 = bf16 out (+bias); 1 = f32 out (+bias+R); 2 = bf16 gelu.
// ---------------------------------------------------------------------------
template<int K_, int EPI>
__global__ __launch_bounds__(256) void mmrk(
    const bf16u* __restrict__ A, const bf16u* __restrict__ Wt,
    const float* __restrict__ bias, const float* __restrict__ R,
    void* __restrict__ Cout, int N)
{
  constexpr int NKB = K_ / 128;
  __shared__ bf16u As[128 * 128];   // 32 KB, [c][m], c = 8-elem k-chunk 0..15
  __shared__ bf16u Bs[64 * 128];    // 16 KB, [c][n]

  const int t = threadIdx.x;
  const int l15 = t & 15, quad = (t >> 4) & 3;
  const int w = t >> 6, wm = w >> 1, wn = w & 1;
  const int m0 = blockIdx.x * 128, n0 = blockIdx.y * 64;

  f32x4 acc[4][2];
  const f32x4 z4 = {0.f, 0.f, 0.f, 0.f};
#pragma unroll
  for (int i = 0; i < 4; ++i) { acc[i][0] = z4; acc[i][1] = z4; }

#pragma unroll
  for (int kb = 0; kb < NKB; ++kb) {
    const int k0 = kb * 128;
    __syncthreads();
#pragma unroll
    for (int p = 0; p < 8; ++p) {   // A: 2048 chunks, g = c*128 + m
      int g = p * 256 + t;
      int m = g & 127, c = g >> 7;
      GLOAD_LDS16(A + (size_t)(m0 + m) * K_ + k0 + c * 8, As + g * 8);
    }
#pragma unroll
    for (int p = 0; p < 4; ++p) {   // B: 1024 chunks, g = c*64 + n
      int g = p * 256 + t;
      int n = g & 63, c = g >> 6;
      GLOAD_LDS16(Wt + (size_t)(n0 + n) * K_ + k0 + c * 8, Bs + g * 8);
    }
    __syncthreads();
#pragma unroll
    for (int ks = 0; ks < 4; ++ks) {
      const int cc = ks * 4 + quad;
      short8 af[4], bf[2];
#pragma unroll
      for (int mt = 0; mt < 4; ++mt)
        af[mt] = *(const short8*)(As + (cc * 128 + wm * 64 + mt * 16 + l15) * 8);
#pragma unroll
      for (int nt = 0; nt < 2; ++nt)
        bf[nt] = *(const short8*)(Bs + (cc * 64 + wn * 32 + nt * 16 + l15) * 8);
#pragma unroll
      for (int mt = 0; mt < 4; ++mt)
#pragma unroll
        for (int nt = 0; nt < 2; ++nt)
          acc[mt][nt] = __builtin_amdgcn_mfma_f32_16x16x32_bf16(
              af[mt], bf[nt], acc[mt][nt], 0, 0, 0);
    }
  }

#pragma unroll
  for (int mt = 0; mt < 4; ++mt) {
#pragma unroll
    for (int nt = 0; nt < 2; ++nt) {
      int col = n0 + wn * 32 + nt * 16 + l15;
      float bia = bias[col];
#pragma unroll
      for (int r = 0; r < 4; ++r) {
        int row = m0 + wm * 64 + mt * 16 + quad * 4 + r;
        size_t idx = (size_t)row * N + col;
        float v = acc[mt][nt][r] + bia;
        if (EPI == 1)      { ((float*)Cout)[idx] = v + R[idx]; }
        else if (EPI == 2) { ((bf16u*)Cout)[idx] = f2bf(gelu_exact(v)); }
        else               { ((bf16u*)Cout)[idx] = f2bf(v); }
      }
    }
  }
}

// ---------------------------------------------------------------------------
// 4x fused 256x256 transpose+convert (z selects which weight). [r3, proven]
// ---------------------------------------------------------------------------
__global__ __launch_bounds__(256) void tcvt4_k(
    const float* __restrict__ s0, const float* __restrict__ s1,
    const float* __restrict__ s2, const float* __restrict__ s3,
    bf16u* __restrict__ d0, bf16u* __restrict__ d1,
    bf16u* __restrict__ d2, bf16u* __restrict__ d3)
{
  const int z = blockIdx.z;
  const float* src = (z == 0) ? s0 : (z == 1) ? s1 : (z == 2) ? s2 : s3;
  bf16u* dst = (z == 0) ? d0 : (z == 1) ? d1 : (z == 2) ? d2 : d3;
  __shared__ float tile[32][33];
  const int tx = threadIdx.x & 31, ty = threadIdx.x >> 5;
  const int kb = blockIdx.x * 32, nb = blockIdx.y * 32;
#pragma unroll
  for (int r = 0; r < 4; ++r)
    tile[ty + 8 * r][tx] = src[(size_t)(kb + ty + 8 * r) * 256 + nb + tx];
  __syncthreads();
#pragma unroll
  for (int r = 0; r < 4; ++r)
    dst[(size_t)(nb + ty + 8 * r) * 256 + kb + tx] = f2bf(tile[tx][ty + 8 * r]);
}

// generic transpose+convert for the FF weights [r3, proven]
__global__ __launch_bounds__(256) void tcvt_k(const float* __restrict__ src,
    bf16u* __restrict__ dst, int K, int N)
{
  __shared__ float tile[32][33];
  const int tx = threadIdx.x & 31, ty = threadIdx.x >> 5;
  const int kb = blockIdx.x * 32, nb = blockIdx.y * 32;
#pragma unroll
  for (int r = 0; r < 4; ++r)
    tile[ty + 8 * r][tx] = src[(size_t)(kb + ty + 8 * r) * N + nb + tx];
  __syncthreads();
#pragma unroll
  for (int r = 0; r < 4; ++r)
    dst[(size_t)(nb + ty + 8 * r) * K + kb + tx] = f2bf(tile[tx][ty + 8 * r]);
}

// fp32 -> bf16 bulk convert, 8 elems/thread [r3, proven]
__global__ __launch_bounds__(256) void cvt_k(const float* __restrict__ X,
    bf16u* __restrict__ Y)
{
  int i = blockIdx.x * 256 + threadIdx.x;
  float4 a = ((const float4*)X)[i * 2];
  float4 b = ((const float4*)X)[i * 2 + 1];
  uint4 o;
  o.x = f2bf(a.x) | ((unsigned)f2bf(a.y) << 16);
  o.y = f2bf(a.z) | ((unsigned)f2bf(a.w) << 16);
  o.z = f2bf(b.x) | ((unsigned)f2bf(b.y) << 16);
  o.w = f2bf(b.z) | ((unsigned)f2bf(b.w) << 16);
  ((uint4*)Y)[i] = o;
}

// concat bq|bk|bv -> bqkv[768] [r3, proven]
__global__ void bcat_k(const float* __restrict__ bq, const float* __restrict__ bk,
                       const float* __restrict__ bv, float* __restrict__ o)
{
  int i = blockIdx.x * 256 + threadIdx.x;
  o[i] = (i < 256) ? bq[i] : (i < 512) ? bk[i - 256] : bv[i - 512];
}

// ---------------------------------------------------------------------------
// MFMA flash attention — EXACT r3 version (two heads per block, grid
// (16,8,8)); proven across 4 passing rounds incl. post-timing checks.
// ---------------------------------------------------------------------------
__global__ __launch_bounds__(256) void attn_k(
    const bf16u* __restrict__ qkv, const int* __restrict__ sb,
    const unsigned char* __restrict__ mask, const float* __restrict__ be,
    bf16u* __restrict__ O)
{
  __shared__ bf16u Kl[2][64][40];
  __shared__ bf16u Vt[2][16][72];
  __shared__ bf16u Pl[4][16][40];
  __shared__ float embl[2][6];

  const int t    = threadIdx.x;
  const int b    = blockIdx.z;
  const int hg   = blockIdx.y;
  const int w    = t >> 6;
  const int lane = t & 63;
  const int l15  = lane & 15;
  const int quad = lane >> 4;
  const int q0w  = blockIdx.x * 64 + w * 16;

  if (t < 12) embl[t / 6][t % 6] = be[(t % 6) * 16 + hg * 2 + t / 6];

  {
    float4 z = {0.f, 0.f, 0.f, 0.f};
    float4* kp = (float4*)&Kl[0][0][0];
    for (int i = t; i < 640; i += 256) kp[i] = z;
  }

  short8 qf[2];
#pragma unroll
  for (int hp = 0; hp < 2; ++hp) {
    uint4 v = {0u, 0u, 0u, 0u};
    if (quad < 2)
      v = *(const uint4*)(qkv + ((size_t)(b * E_) + q0w + l15) * 768 +
                          (hg * 2 + hp) * 16 + quad * 8);
    else if (quad == 2)
      v.x = 0x3F80u;
    union { uint4 u; short8 s; } c; c.u = v;
    qf[hp] = c.s;
  }

  const int s_hp   = t >> 7;
  const int s_key  = (t >> 1) & 63;
  const int s_half = t & 1;
  const size_t kvbase = (size_t)b * E_ * 768;
  const int* sbp = sb + ((size_t)b * E_ + q0w) * E_;

  f32x4 accO[2];
  const f32x4 z4 = {0.f, 0.f, 0.f, 0.f};
  accO[0] = z4; accO[1] = z4;
  float lsum[2][4] = {};

  for (int k0 = 0; k0 < E_; k0 += 64) {
    int sbv[2][2][4];
#pragma unroll
    for (int s2 = 0; s2 < 2; ++s2)
#pragma unroll
      for (int f = 0; f < 2; ++f)
#pragma unroll
        for (int r = 0; r < 4; ++r)
          sbv[s2][f][r] = sbp[(size_t)(quad * 4 + r) * E_ + k0 + s2 * 32 + f * 16 + l15];

    __syncthreads();
    {
      const bf16u* kq = qkv + kvbase + (size_t)(k0 + s_key) * 768 + 256 +
                        (hg * 2 + s_hp) * 16 + s_half * 8;
      uint4 kw = *(const uint4*)kq;
      uint4 vw = *(const uint4*)(kq + 256);
      *(uint4*)&Kl[s_hp][s_key][s_half * 8] = kw;
      const int col = (s_key >> 5) * 32 + ((s_key & 15) << 1) + ((s_key >> 4) & 1);
      union { uint4 u; bf16u e[8]; } vc; vc.u = vw;
#pragma unroll
      for (int j = 0; j < 8; ++j)
        Vt[s_hp][s_half * 8 + j][col] = vc.e[j];
      if (s_half == 0) {
        unsigned char mv = mask[b * E_ + k0 + s_key];
        Kl[s_hp][s_key][16] = mv ? (bf16u)0xCF6E : (bf16u)0;
      }
    }
    __syncthreads();

#pragma unroll
    for (int hp = 0; hp < 2; ++hp) {
#pragma unroll
      for (int s2 = 0; s2 < 2; ++s2) {
        short8 kf0 = *(const short8*)&Kl[hp][s2 * 32 + l15][quad * 8];
        short8 kf1 = *(const short8*)&Kl[hp][s2 * 32 + 16 + l15][quad * 8];
        f32x4 sc0 = __builtin_amdgcn_mfma_f32_16x16x32_bf16(qf[hp], kf0, z4, 0, 0, 0);
        f32x4 sc1 = __builtin_amdgcn_mfma_f32_16x16x32_bf16(qf[hp], kf1, z4, 0, 0, 0);
#pragma unroll
        for (int r = 0; r < 4; ++r) {
          float w0 = embl[hp][sbv[s2][0][r]];
          float w1 = embl[hp][sbv[s2][1][r]];
          float p0 = __expf(fmaf(sc0[r], 0.25f, w0));
          float p1 = __expf(fmaf(sc1[r], 0.25f, w1));
          unsigned u0 = __float_as_uint(p0) & 0xffff0000u;
          unsigned u1 = __float_as_uint(p1) & 0xffff0000u;
          lsum[hp][r] += __uint_as_float(u0) + __uint_as_float(u1);
          *(unsigned*)&Pl[w][quad * 4 + r][l15 * 2] = (__float_as_uint(p0) >> 16) | u1;
        }
        short8 pf = *(const short8*)&Pl[w][l15][quad * 8];
        short8 vf = *(const short8*)&Vt[hp][l15][s2 * 32 + quad * 8];
        accO[hp] = __builtin_amdgcn_mfma_f32_16x16x32_bf16(pf, vf, accO[hp], 0, 0, 0);
      }
    }
  }

#pragma unroll
  for (int off = 1; off <= 8; off <<= 1)
#pragma unroll
    for (int hp = 0; hp < 2; ++hp)
#pragma unroll
      for (int r = 0; r < 4; ++r)
        lsum[hp][r] += __shfl_xor(lsum[hp][r], off, 64);

#pragma unroll
  for (int hp = 0; hp < 2; ++hp) {
#pragma unroll
    for (int r = 0; r < 4; ++r) {
      float o = accO[hp][r] / lsum[hp][r];
      O[((size_t)(b * E_) + q0w + quad * 4 + r) * 256 + (hg * 2 + hp) * 16 + l15] = f2bf(o);
    }
  }
}

// ---------------------------------------------------------------------------
// LayerNorm, one wave per row of 256. DUAL: also write bf16 copy. [r3]
// ---------------------------------------------------------------------------
template<int DUAL>
__global__ __launch_bounds__(256) void ln_k(
    const float* __restrict__ X, const float* __restrict__ g,
    const float* __restrict__ bta, float* __restrict__ Y, bf16u* __restrict__ Yb)
{
  const int row  = blockIdx.x * 4 + (threadIdx.x >> 6);
  const int lane = threadIdx.x & 63;
  float4 v = *(const float4*)(X + (size_t)row * D_ + lane * 4);
  float s  = v.x + v.y + v.z + v.w;
  float ss = v.x * v.x + v.y * v.y + v.z * v.z + v.w * v.w;
#pragma unroll
  for (int off = 32; off; off >>= 1) {
    s  += __shfl_xor(s, off, 64);
    ss += __shfl_xor(ss, off, 64);
  }
  float mu  = s * (1.f / 256.f);
  float var = ss * (1.f / 256.f) - mu * mu;
  float rs  = 1.f / sqrtf(var + 1e-5f);
  float4 gv = *(const float4*)(g + lane * 4);
  float4 bv = *(const float4*)(bta + lane * 4);
  float4 o;
  o.x = (v.x - mu) * rs * gv.x + bv.x;
  o.y = (v.y - mu) * rs * gv.y + bv.y;
  o.z = (v.z - mu) * rs * gv.z + bv.z;
  o.w = (v.w - mu) * rs * gv.w + bv.w;
  *(float4*)(Y + (size_t)row * D_ + lane * 4) = o;
  if (DUAL) {
    uint2 p;
    p.x = f2bf(o.x) | ((unsigned)f2bf(o.y) << 16);
    p.y = f2bf(o.z) | ((unsigned)f2bf(o.w) << 16);
    *(uint2*)(Yb + (size_t)row * D_ + lane * 4) = p;
  }
}

// ---------------------------------------------------------------------------
extern "C" void kernel_launch(void* const* d_in, const int* in_sizes, int n_in,
                              void* d_out, int out_size, void* d_ws, size_t ws_size,
                              hipStream_t stream) {
  const float* x   = (const float*)d_in[0];
  const int*   sb  = (const int*)d_in[1];
  const unsigned char* mask = (const unsigned char*)d_in[2];
  const float* Wq  = (const float*)d_in[3];
  const float* bq  = (const float*)d_in[4];
  const float* Wk  = (const float*)d_in[5];
  const float* bk  = (const float*)d_in[6];
  const float* Wv  = (const float*)d_in[7];
  const float* bv  = (const float*)d_in[8];
  const float* Wo  = (const float*)d_in[9];
  const float* bo  = (const float*)d_in[10];
  const float* be  = (const float*)d_in[11];
  const float* g1  = (const float*)d_in[12];
  const float* b1  = (const float*)d_in[13];
  const float* Wf1 = (const float*)d_in[14];
  const float* bf1 = (const float*)d_in[15];
  const float* Wf2 = (const float*)d_in[16];
  const float* bf2 = (const float*)d_in[17];
  const float* g2  = (const float*)d_in[18];
  const float* b2  = (const float*)d_in[19];
  float* out = (float*)d_out;

  // workspace layout (byte offsets) — r3's exact layout; peak ~42 MB
  char* ws = (char*)d_ws;
  bf16u* Wqkvt = (bf16u*)(ws + 0);          // 768*256*2
  bf16u* Wot   = (bf16u*)(ws + 393216);     // 256*256*2
  bf16u* Wf1t  = (bf16u*)(ws + 524288);     // 1024*256*2
  bf16u* Wf2t  = (bf16u*)(ws + 1048576);    // 256*1024*2
  float* bqkv  = (float*)(ws + 1572864);    // 768*4
  bf16u* xb    = (bf16u*)(ws + 2097152);    // 4 MB   [dead after qkv gemm]
  bf16u* qkv   = (bf16u*)(ws + 6291456);    // 12 MB  [dead after attn]
  bf16u* att   = (bf16u*)(ws + 18874368);   // 4 MB
  float* t1    = (float*)(ws + 23068672);   // 8 MB   [dead after ln1]
  float* x1    = (float*)(ws + 31457280);   // 8 MB
  bf16u* x1b   = (bf16u*)(ws + 39845888);   // 4 MB
  bf16u* ffh   = (bf16u*)(ws + 2097152);    // 16 MB, reuses xb+qkv
  float* t2    = (float*)(ws + 18874368);   // 8 MB, reuses att+t1

  dim3 blk(256);

  tcvt4_k<<<dim3(8, 8, 4), blk, 0, stream>>>(Wq, Wk, Wv, Wo,
      Wqkvt, Wqkvt + 65536, Wqkvt + 131072, Wot);
  tcvt_k<<<dim3(8, 32), blk, 0, stream>>>(Wf1, Wf1t, 256, 1024);
  tcvt_k<<<dim3(32, 8), blk, 0, stream>>>(Wf2, Wf2t, 1024, 256);
  bcat_k<<<3, blk, 0, stream>>>(bq, bk, bv, bqkv);
  cvt_k<<<1024, blk, 0, stream>>>(x, xb);

  // QKV projection (fused, N=768) -> qkv bf16
  mmrk<256, 0><<<dim3(64, 12), blk, 0, stream>>>(xb, Wqkvt, bqkv, nullptr,
                                                 qkv, 768);
  // MFMA flash attention (r3 proven) -> att bf16
  attn_k<<<dim3(16, 8, 8), blk, 0, stream>>>(qkv, sb, mask, be, att);

  // out-proj + residual -> t1 fp32; ln1 -> x1 fp32 + x1b bf16
  mmrk<256, 1><<<dim3(64, 4), blk, 0, stream>>>(att, Wot, bo, x, t1, 256);
  ln_k<1><<<M_ / 4, blk, 0, stream>>>(t1, g1, b1, x1, x1b);

  // FFN
  mmrk<256, 2><<<dim3(64, 16), blk, 0, stream>>>(x1b, Wf1t, bf1, nullptr,
                                                 ffh, 1024);
  mmrk<1024, 1><<<dim3(64, 4), blk, 0, stream>>>(ffh, Wf2t, bf2, x1, t2, 256);
  ln_k<0><<<M_ / 4, blk, 0, stream>>>(t2, g2, b2, out, nullptr);
}